// Round 10
// baseline (403.201 us; speedup 1.0000x reference)
//
#include <hip/hip_runtime.h>

typedef unsigned short u16;
typedef unsigned int u32;
typedef __attribute__((ext_vector_type(8))) short bf16x8;
typedef __attribute__((ext_vector_type(4))) float f32x4;

#define KDIM   512
#define NROWS  1024
#define NCLS   100000
#define CPAD   100096   // 782*128
#define NSTRIP 782      // 128-wide column strips
#define NMT    8        // 1024/128
#define NWG    (NSTRIP*NMT)   // 6256

#define COS_M_C   0.8775825618903728f
#define SIN_M_C   0.4794255386042030f
#define THRESH_C  (-0.8775825618903728f)
#define MM_C      0.2397127693021015f
#define S_C       64.0f

__device__ __forceinline__ u16 f2bf(float f) {
    u32 x = __float_as_uint(f);
    x += 0x7fffu + ((x >> 16) & 1u);   // RNE
    return (u16)(x >> 16);
}
__device__ __forceinline__ float bf2f(u16 u) {
    return __uint_as_float(((u32)u) << 16);
}
__device__ __forceinline__ u32 pack2(float a, float b) {
    return (u32)f2bf(a) | ((u32)f2bf(b) << 16);
}

// Image geometry (R8, unchanged): per (tile, kt) an 8 KB block = 128 rows x
// 32 k bf16 = 64 lines of 128 B. Chunk (r,q) at line r>>1, slot
// ((r&1)*4 + q + (r>>1)) & 7. Key property for R10: a wave's fragment set
// {rows w..w+15, all q} occupies EXACTLY lines (w>>1)..(w>>1)+7 = one
// contiguous 1 KB block -> per-lane-addressed b128 global loads are fully
// coalesced. Slot invariant under r+=16 -> fragment m stride = 512 u16.
__device__ __forceinline__ int imgoff(int r, int q) {   // u16 units
    return (r >> 1) * 64 + ((((r & 1) << 2) + q + (r >> 1)) & 7) * 8;
}

// ---------------- kernel 1: row-normalize embeddings ----------------
__global__ __launch_bounds__(64)
void norm_emb_k(const float* __restrict__ emb, float* __restrict__ Af,
                u16* __restrict__ Aw) {
    const int i = blockIdx.x, l = threadIdx.x;
    const float* e = emb + i * KDIM;
    float4 v0 = *(const float4*)(e + l * 8);
    float4 v1 = *(const float4*)(e + l * 8 + 4);
    float s = v0.x*v0.x + v0.y*v0.y + v0.z*v0.z + v0.w*v0.w
            + v1.x*v1.x + v1.y*v1.y + v1.z*v1.z + v1.w*v1.w;
    #pragma unroll
    for (int o = 1; o < 64; o <<= 1) s += __shfl_xor(s, o);
    float inv = rsqrtf(s);
    float4 n0 = make_float4(v0.x*inv, v0.y*inv, v0.z*inv, v0.w*inv);
    float4 n1 = make_float4(v1.x*inv, v1.y*inv, v1.z*inv, v1.w*inv);
    *(float4*)(Af + i*KDIM + l*8)     = n0;
    *(float4*)(Af + i*KDIM + l*8 + 4) = n1;
    // lane l owns k = l*8..l*8+7 -> kt = l>>2, chunk q = l&3
    const int mt = i >> 7, row = i & 127;
    uint4 w;
    w.x = pack2(n0.x, n0.y);
    w.y = pack2(n0.z, n0.w);
    w.z = pack2(n1.x, n1.y);
    w.w = pack2(n1.z, n1.w);
    *(uint4*)(Aw + mt*65536 + (l>>2)*4096 + imgoff(row, l & 3)) = w;
}

// ------- kernel 2: transpose+convert W [512][100000]f32 -> Bn image + norms
__global__ __launch_bounds__(128)
void transpose_norm_k(const float* __restrict__ Kg, u16* __restrict__ Bn,
                      float* __restrict__ kinv) {
    __shared__ float Ls[32 * 132];           // 32 k-rows x 128 cols, pad 132
    const int t  = threadIdx.x;
    const int jb = blockIdx.x * 128;
    const int j  = jb + t;
    u16* bstrip = Bn + (size_t)blockIdx.x * 65536;   // 16 kt * 4096 u16
    float acc = 0.f;
    for (int kc = 0; kc < 16; ++kc) {        // kc == kt (32 k each)
        #pragma unroll
        for (int it = 0; it < 8; ++it) {
            int fid  = it * 128 + t;
            int r    = fid >> 5;
            int c4   = (fid & 31) * 4;
            int gcol = jb + c4;
            float4 v;
            if (gcol + 3 < NCLS) {
                v = *(const float4*)(Kg + (kc*32 + r) * NCLS + gcol);
            } else {
                v.x = (gcol + 0 < NCLS) ? Kg[(kc*32 + r)*NCLS + gcol + 0] : 0.f;
                v.y = (gcol + 1 < NCLS) ? Kg[(kc*32 + r)*NCLS + gcol + 1] : 0.f;
                v.z = (gcol + 2 < NCLS) ? Kg[(kc*32 + r)*NCLS + gcol + 2] : 0.f;
                v.w = (gcol + 3 < NCLS) ? Kg[(kc*32 + r)*NCLS + gcol + 3] : 0.f;
            }
            *(float4*)(Ls + r * 132 + c4) = v;
        }
        __syncthreads();
        #pragma unroll
        for (int q = 0; q < 4; ++q) {        // chunk q covers k = kc*32+q*8..
            u16 u[8];
            #pragma unroll
            for (int e = 0; e < 8; ++e) {
                float v = Ls[(q*8 + e) * 132 + t];
                acc += v * v;
                u[e] = f2bf(v);
            }
            uint4 w;
            w.x = (u32)u[0] | ((u32)u[1] << 16);
            w.y = (u32)u[2] | ((u32)u[3] << 16);
            w.z = (u32)u[4] | ((u32)u[5] << 16);
            w.w = (u32)u[6] | ((u32)u[7] << 16);
            *(uint4*)(bstrip + kc*4096 + imgoff(t, q)) = w;
        }
        __syncthreads();
    }
    kinv[j] = rsqrtf(fmaxf(acc, 1e-30f));
}

// ---------------- kernel 3: per-row target logit & margins ----------------
__global__ __launch_bounds__(64)
void target_k(const float* __restrict__ Af, const u16* __restrict__ Bn,
              const float* __restrict__ kinv, const int* __restrict__ label,
              float* __restrict__ tgt, float* __restrict__ ctm,
              float* __restrict__ fin) {
    const int i = blockIdx.x, l = threadIdx.x;
    const int lab = label[i];
    float4 a0 = *(const float4*)(Af + i * KDIM + l * 8);
    float4 a1 = *(const float4*)(Af + i * KDIM + l * 8 + 4);
    uint4 bv = *(const uint4*)(Bn + (size_t)(lab >> 7) * 65536
               + (l >> 2) * 4096 + imgoff(lab & 127, l & 3));
    float d = a0.x * bf2f((u16)(bv.x & 0xffff)) + a0.y * bf2f((u16)(bv.x >> 16))
            + a0.z * bf2f((u16)(bv.y & 0xffff)) + a0.w * bf2f((u16)(bv.y >> 16))
            + a1.x * bf2f((u16)(bv.z & 0xffff)) + a1.y * bf2f((u16)(bv.z >> 16))
            + a1.z * bf2f((u16)(bv.w & 0xffff)) + a1.w * bf2f((u16)(bv.w >> 16));
    #pragma unroll
    for (int o = 1; o < 64; o <<= 1) d += __shfl_xor(d, o);
    if (l == 0) {
        float c = d * kinv[lab];
        c = fminf(fmaxf(c, -1.f), 1.f);
        tgt[i] = c;
        float sn = sqrtf(fmaxf(1.f - c*c, 0.f));
        float cm = c * COS_M_C - sn * SIN_M_C;
        ctm[i] = cm;
        fin[i] = (c > THRESH_C) ? cm : (c - MM_C);
    }
}

// ---------------- kernel 4: t_new scalar ----------------
__global__ __launch_bounds__(256)
void tnew_k(const float* __restrict__ tgt, const float* __restrict__ tin,
            float* __restrict__ tnw) {
    __shared__ float red[256];
    const int t = threadIdx.x;
    float s = tgt[t] + tgt[t + 256] + tgt[t + 512] + tgt[t + 768];
    red[t] = s;
    __syncthreads();
    for (int o = 128; o > 0; o >>= 1) {
        if (t < o) red[t] += red[t + o];
        __syncthreads();
    }
    if (t == 0) tnw[0] = red[0] * (0.01f / 1024.f) + 0.99f * tin[0];
}

// ------ kernel 5: LDS-FREE 128x128 GEMM: fragments direct L2 -> VGPR ------
// 4 waves (2x2), wave-tile 64x64. No LDS, no barriers: each wave loads its
// MFMA fragments straight from the pre-swizzled HBM/L2 images with b128
// per-lane loads (one wave-load = one contiguous 1 KB block). Register
// double-buffer (2 named sets, static indexing) hides L2 latency; compiler
// inserts counted vmcnt.
__global__ __launch_bounds__(256)
void gemm_k(const u16* __restrict__ A, const u16* __restrict__ B,
            const float* __restrict__ kinv, const float* __restrict__ ctm,
            const float* __restrict__ fin, const int* __restrict__ label,
            const float* __restrict__ tnwp, float* __restrict__ out) {
    const int tid  = threadIdx.x;
    const int wave = tid >> 6, lane = tid & 63;

    // XCD-chunked swizzle (6256 = 8*782, exact): mt fast -> B strip shared.
    const int L  = blockIdx.x;
    const int w  = (L & 7) * NSTRIP + (L >> 3);
    const int mt = w & 7;
    const int cs = w >> 3;
    const int m0 = mt * 128;
    const int j0 = cs * 128;
    const int wr = (wave >> 1) * 64;
    const int wc = (wave & 1) * 64;

    f32x4 acc[4][4] = {};

    const int lr = lane & 15, q = lane >> 4;
    // per-lane fragment base pointers (u16 units); fragment m/n: +512 each,
    // k-step: +4096.
    const u16* aP = A + mt * 65536 + imgoff(wr + lr, q);
    const u16* bP = B + (size_t)cs * 65536 + imgoff(wc + lr, q);

    bf16x8 a0[4], b0[4], a1[4], b1[4];

#define LOADF(AS, BS, kt) do {                                       \
    const u16* ap_ = aP + (kt) * 4096;                               \
    const u16* bp_ = bP + (kt) * 4096;                               \
    _Pragma("unroll")                                                \
    for (int m = 0; m < 4; ++m) AS[m] = *(const bf16x8*)(ap_ + m * 512); \
    _Pragma("unroll")                                                \
    for (int n = 0; n < 4; ++n) BS[n] = *(const bf16x8*)(bp_ + n * 512); \
} while (0)

#define MFMA16(AS, BS) do {                                          \
    _Pragma("unroll")                                                \
    for (int m = 0; m < 4; ++m)                                      \
        _Pragma("unroll")                                            \
        for (int n = 0; n < 4; ++n)                                  \
            acc[m][n] = __builtin_amdgcn_mfma_f32_16x16x32_bf16(     \
                            AS[m], BS[n], acc[m][n], 0, 0, 0);       \
} while (0)

    LOADF(a0, b0, 0);
    #pragma unroll
    for (int kt = 0; kt < 16; kt += 2) {
        if (kt + 1 < 16) LOADF(a1, b1, kt + 1);
        MFMA16(a0, b0);
        if (kt + 2 < 16) LOADF(a0, b0, kt + 2);
        if (kt + 1 < 16) MFMA16(a1, b1);
    }
#undef LOADF
#undef MFMA16

    // fused epilogue (scattered dword, R4/R7/R8-validated)
    const float tnew = *tnwp;
    const int colbase = j0 + wc + (lane & 15);
    float kv[4];
    int cols[4];
    #pragma unroll
    for (int n = 0; n < 4; ++n) {
        cols[n] = colbase + n * 16;
        kv[n] = kinv[cols[n]];
    }
    #pragma unroll
    for (int m = 0; m < 4; ++m) {
        const int rb = m0 + wr + m * 16 + (lane >> 4) * 4;
        #pragma unroll
        for (int r = 0; r < 4; ++r) {
            const int row = rb + r;
            const int lab = label[row];
            const float ct = ctm[row];
            const float fv = fin[row];
            float* orow = out + (size_t)row * NCLS;
            #pragma unroll
            for (int n = 0; n < 4; ++n) {
                float c = acc[m][n][r] * kv[n];
                c = fminf(fmaxf(c, -1.f), 1.f);
                float v = (c > ct) ? c * (tnew + c) : c;
                v = (cols[n] == lab) ? fv : v;
                if (cols[n] < NCLS)
                    orow[cols[n]] = v * S_C;
            }
        }
    }
}

extern "C" void kernel_launch(void* const* d_in, const int* in_sizes, int n_in,
                              void* d_out, int out_size, void* d_ws, size_t ws_size,
                              hipStream_t stream) {
    const float* emb = (const float*)d_in[0];
    const float* Kg  = (const float*)d_in[1];
    const float* tin = (const float*)d_in[2];
    const int*   lab = (const int*)d_in[3];
    float* out = (float*)d_out;

    char* w = (char*)d_ws;
    u16*   Bn   = (u16*)w;                         // 782*65536*2 = 102,498,304
    u16*   Aw   = (u16*)(w + 102498304);           // 8*65536*2   =   1,048,576
    float* Af   = (float*)(w + 103546880);         // 1024*512*4  =   2,097,152
    float* kinv = (float*)(w + 105644032);         // CPAD*4      =     400,384
    float* tgt  = (float*)(w + 106044416);
    float* ctmv = (float*)(w + 106048512);
    float* finv = (float*)(w + 106052608);
    float* tnw  = (float*)(w + 106056704);

    norm_emb_k<<<NROWS, 64, 0, stream>>>(emb, Af, Aw);
    transpose_norm_k<<<NSTRIP, 128, 0, stream>>>(Kg, Bn, kinv);
    target_k<<<NROWS, 64, 0, stream>>>(Af, Bn, kinv, lab, tgt, ctmv, finv);
    tnew_k<<<1, 256, 0, stream>>>(tgt, tin, tnw);
    gemm_k<<<NWG, 256, 0, stream>>>(
        Aw, Bn, kinv, ctmv, finv, lab, tnw, out);
}

// Round 11
// 386.551 us; speedup vs baseline: 1.0431x; 1.0431x over previous
//
#include <hip/hip_runtime.h>

typedef unsigned short u16;
typedef unsigned int u32;
typedef __attribute__((ext_vector_type(8))) short bf16x8;
typedef __attribute__((ext_vector_type(4))) float f32x4;

#define KDIM   512
#define NROWS  1024
#define NCLS   100000
#define CPAD   100096   // 1564*64
#define NSTRIP 1564     // 64-wide column strips
#define NMT    8        // 1024/128
#define NWG    (NSTRIP*NMT)   // 12512

#define COS_M_C   0.8775825618903728f
#define SIN_M_C   0.4794255386042030f
#define THRESH_C  (-0.8775825618903728f)
#define MM_C      0.2397127693021015f
#define S_C       64.0f

__device__ __forceinline__ u16 f2bf(float f) {
    u32 x = __float_as_uint(f);
    x += 0x7fffu + ((x >> 16) & 1u);   // RNE
    return (u16)(x >> 16);
}
__device__ __forceinline__ float bf2f(u16 u) {
    return __uint_as_float(((u32)u) << 16);
}
__device__ __forceinline__ u32 pack2(float a, float b) {
    return (u32)f2bf(a) | ((u32)f2bf(b) << 16);
}

// Image geometry (R8-validated, SQ_LDS_BANK_CONFLICT == 0):
// per (tile, kt): rows x 32 k bf16 as lines of 128 B; line L holds rows
// 2L, 2L+1; chunk (r,q) at line r>>1, slot ((r&1)*4 + q + (r>>1)) & 7.
// Slot invariant under r += 16 -> fragment stride 512 u16.
__device__ __forceinline__ int imgoff(int r, int q) {   // u16 units
    return (r >> 1) * 64 + ((((r & 1) << 2) + q + (r >> 1)) & 7) * 8;
}

__device__ __forceinline__ void gld16(const void* g, void* l) {
    __builtin_amdgcn_global_load_lds(
        (const __attribute__((address_space(1))) void*)g,
        (__attribute__((address_space(3))) void*)l, 16, 0, 0);
}

// A image: [8 mt][16 kt][128 rows x 32 k]  (65536 u16 per mt, 4096 per kt)
// B image: [1564 strip][16 kt][64 cols x 32 k] (32768 u16 per strip, 2048/kt)

// ---------------- kernel 1: row-normalize embeddings ----------------
__global__ __launch_bounds__(64)
void norm_emb_k(const float* __restrict__ emb, float* __restrict__ Af,
                u16* __restrict__ Aw) {
    const int i = blockIdx.x, l = threadIdx.x;
    const float* e = emb + i * KDIM;
    float4 v0 = *(const float4*)(e + l * 8);
    float4 v1 = *(const float4*)(e + l * 8 + 4);
    float s = v0.x*v0.x + v0.y*v0.y + v0.z*v0.z + v0.w*v0.w
            + v1.x*v1.x + v1.y*v1.y + v1.z*v1.z + v1.w*v1.w;
    #pragma unroll
    for (int o = 1; o < 64; o <<= 1) s += __shfl_xor(s, o);
    float inv = rsqrtf(s);
    float4 n0 = make_float4(v0.x*inv, v0.y*inv, v0.z*inv, v0.w*inv);
    float4 n1 = make_float4(v1.x*inv, v1.y*inv, v1.z*inv, v1.w*inv);
    *(float4*)(Af + i*KDIM + l*8)     = n0;
    *(float4*)(Af + i*KDIM + l*8 + 4) = n1;
    // lane l owns k = l*8..l*8+7 -> kt = l>>2, chunk q = l&3
    const int mt = i >> 7, row = i & 127;
    uint4 w;
    w.x = pack2(n0.x, n0.y);
    w.y = pack2(n0.z, n0.w);
    w.z = pack2(n1.x, n1.y);
    w.w = pack2(n1.z, n1.w);
    *(uint4*)(Aw + mt*65536 + (l>>2)*4096 + imgoff(row, l & 3)) = w;
}

// ------- kernel 2: transpose+convert W [512][100000]f32 -> Bn image + norms
__global__ __launch_bounds__(128)
void transpose_norm_k(const float* __restrict__ Kg, u16* __restrict__ Bn,
                      float* __restrict__ kinv) {
    __shared__ float Ls[32 * 132];           // 32 k-rows x 128 cols, pad 132
    const int t  = threadIdx.x;
    const int jb = blockIdx.x * 128;
    const int j  = jb + t;
    float acc = 0.f;
    for (int kc = 0; kc < 16; ++kc) {        // kc == kt (32 k each)
        #pragma unroll
        for (int it = 0; it < 8; ++it) {
            int fid  = it * 128 + t;
            int r    = fid >> 5;
            int c4   = (fid & 31) * 4;
            int gcol = jb + c4;
            float4 v;
            if (gcol + 3 < NCLS) {
                v = *(const float4*)(Kg + (kc*32 + r) * NCLS + gcol);
            } else {
                v.x = (gcol + 0 < NCLS) ? Kg[(kc*32 + r)*NCLS + gcol + 0] : 0.f;
                v.y = (gcol + 1 < NCLS) ? Kg[(kc*32 + r)*NCLS + gcol + 1] : 0.f;
                v.z = (gcol + 2 < NCLS) ? Kg[(kc*32 + r)*NCLS + gcol + 2] : 0.f;
                v.w = (gcol + 3 < NCLS) ? Kg[(kc*32 + r)*NCLS + gcol + 3] : 0.f;
            }
            *(float4*)(Ls + r * 132 + c4) = v;
        }
        __syncthreads();
        #pragma unroll
        for (int q = 0; q < 4; ++q) {        // chunk q covers k = kc*32+q*8..
            u16 u[8];
            #pragma unroll
            for (int e = 0; e < 8; ++e) {
                float v = Ls[(q*8 + e) * 132 + t];
                acc += v * v;
                u[e] = f2bf(v);
            }
            uint4 w;
            w.x = (u32)u[0] | ((u32)u[1] << 16);
            w.y = (u32)u[2] | ((u32)u[3] << 16);
            w.z = (u32)u[4] | ((u32)u[5] << 16);
            w.w = (u32)u[6] | ((u32)u[7] << 16);
            *(uint4*)(Bn + (size_t)(j >> 6) * 32768 + kc * 2048
                      + imgoff(j & 63, q)) = w;
        }
        __syncthreads();
    }
    kinv[j] = rsqrtf(fmaxf(acc, 1e-30f));
}

// ---------------- kernel 3: per-row target logit & margins ----------------
__global__ __launch_bounds__(64)
void target_k(const float* __restrict__ Af, const u16* __restrict__ Bn,
              const float* __restrict__ kinv, const int* __restrict__ label,
              float* __restrict__ tgt, float* __restrict__ ctm,
              float* __restrict__ fin) {
    const int i = blockIdx.x, l = threadIdx.x;
    const int lab = label[i];
    float4 a0 = *(const float4*)(Af + i * KDIM + l * 8);
    float4 a1 = *(const float4*)(Af + i * KDIM + l * 8 + 4);
    uint4 bv = *(const uint4*)(Bn + (size_t)(lab >> 6) * 32768
               + (l >> 2) * 2048 + imgoff(lab & 63, l & 3));
    float d = a0.x * bf2f((u16)(bv.x & 0xffff)) + a0.y * bf2f((u16)(bv.x >> 16))
            + a0.z * bf2f((u16)(bv.y & 0xffff)) + a0.w * bf2f((u16)(bv.y >> 16))
            + a1.x * bf2f((u16)(bv.z & 0xffff)) + a1.y * bf2f((u16)(bv.z >> 16))
            + a1.z * bf2f((u16)(bv.w & 0xffff)) + a1.w * bf2f((u16)(bv.w >> 16));
    #pragma unroll
    for (int o = 1; o < 64; o <<= 1) d += __shfl_xor(d, o);
    if (l == 0) {
        float c = d * kinv[lab];
        c = fminf(fmaxf(c, -1.f), 1.f);
        tgt[i] = c;
        float sn = sqrtf(fmaxf(1.f - c*c, 0.f));
        float cm = c * COS_M_C - sn * SIN_M_C;
        ctm[i] = cm;
        fin[i] = (c > THRESH_C) ? cm : (c - MM_C);
    }
}

// ---------------- kernel 4: t_new scalar ----------------
__global__ __launch_bounds__(256)
void tnew_k(const float* __restrict__ tgt, const float* __restrict__ tin,
            float* __restrict__ tnw) {
    __shared__ float red[256];
    const int t = threadIdx.x;
    float s = tgt[t] + tgt[t + 256] + tgt[t + 512] + tgt[t + 768];
    red[t] = s;
    __syncthreads();
    for (int o = 128; o > 0; o >>= 1) {
        if (t < o) red[t] += red[t + o];
        __syncthreads();
    }
    if (t == 0) tnw[0] = red[0] * (0.01f / 1024.f) + 0.99f * tin[0];
}

// ------- kernel 5: 128x64 bf16 MFMA GEMM, 6 blocks/CU (75% occupancy) -----
// BK=32, 4 waves (2x2), wave-tile 64x32, LDS 24KB double-buffered.
// Same counted-vmcnt 2-barrier loop as R8; zero-conflict imgoff images.
__global__ __launch_bounds__(256, 6)
void gemm_k(const u16* __restrict__ A, const u16* __restrict__ B,
            const float* __restrict__ kinv, const float* __restrict__ ctm,
            const float* __restrict__ fin, const int* __restrict__ label,
            const float* __restrict__ tnwp, float* __restrict__ out) {
    __shared__ __align__(16) u16 As[2][4096];   // 2 x 8 KB
    __shared__ __align__(16) u16 Bs[2][2048];   // 2 x 4 KB
    const int tid  = threadIdx.x;
    const int wave = tid >> 6, lane = tid & 63;

    // XCD-chunked bijective swizzle (12512 = 8*1564): mt fast within XCD.
    const int L  = blockIdx.x;
    const int w  = (L & 7) * NSTRIP + (L >> 3);
    const int mt = w & 7;
    const int cs = w >> 3;
    const int m0 = mt * 128;
    const int j0 = cs * 64;
    const int wr = (wave >> 1) * 64;   // wave M offset
    const int wc = (wave & 1) * 32;    // wave N offset

    f32x4 acc[4][2] = {};

    const u16* gA = A + mt * 65536 + tid * 8;
    const u16* gB = B + (size_t)cs * 32768 + tid * 8;

    const int lr = lane & 15, q = lane >> 4;
    const int aBase = imgoff(wr + lr, q);   // + m*512 per fragment (m=0..3)
    const int bBase = imgoff(wc + lr, q);   // + n*512 per fragment (n=0..1)

#define STAGE(b, kt) do {                                        \
    gld16(gA + (kt)*4096,        &As[b][tid*8]);                 \
    gld16(gA + (kt)*4096 + 2048, &As[b][tid*8 + 2048]);          \
    gld16(gB + (kt)*2048,        &Bs[b][tid*8]);                 \
} while (0)

    STAGE(0, 0);
    #pragma unroll 2
    for (int kt = 0; kt < 16; ++kt) {
        const int cur = kt & 1;
        if (kt < 15) {
            STAGE(cur ^ 1, kt + 1);
            asm volatile("s_waitcnt vmcnt(3)" ::: "memory");
        } else {
            asm volatile("s_waitcnt vmcnt(0)" ::: "memory");
        }
        __builtin_amdgcn_s_barrier();    // buf[cur] fully staged

        bf16x8 af[4], bfr[2];
        #pragma unroll
        for (int m = 0; m < 4; ++m)
            af[m] = *(const bf16x8*)(As[cur] + aBase + m * 512);
        #pragma unroll
        for (int n = 0; n < 2; ++n)
            bfr[n] = *(const bf16x8*)(Bs[cur] + bBase + n * 512);
        asm volatile("s_waitcnt lgkmcnt(0)" ::: "memory");
        __builtin_amdgcn_sched_barrier(0);   // rule 18
        __builtin_amdgcn_s_barrier();        // all waves done reading cur

        #pragma unroll
        for (int m = 0; m < 4; ++m)
            #pragma unroll
            for (int n = 0; n < 2; ++n)
                acc[m][n] = __builtin_amdgcn_mfma_f32_16x16x32_bf16(
                                af[m], bfr[n], acc[m][n], 0, 0, 0);
    }
#undef STAGE

    // fused epilogue (scattered dword, validated WRITE_SIZE == 400 MB exact)
    const float tnew = *tnwp;
    const int colbase = j0 + wc + lr;
    float kv[2];
    int cols[2];
    #pragma unroll
    for (int n = 0; n < 2; ++n) {
        cols[n] = colbase + n * 16;
        kv[n] = (cols[n] < NCLS) ? kinv[cols[n]] : 0.f;
    }
    #pragma unroll
    for (int m = 0; m < 4; ++m) {
        const int rb = m0 + wr + m * 16 + q * 4;
        #pragma unroll
        for (int r = 0; r < 4; ++r) {
            const int row = rb + r;
            const int lab = label[row];
            const float ct = ctm[row];
            const float fv = fin[row];
            float* orow = out + (size_t)row * NCLS;
            #pragma unroll
            for (int n = 0; n < 2; ++n) {
                float c = acc[m][n][r] * kv[n];
                c = fminf(fmaxf(c, -1.f), 1.f);
                float v = (c > ct) ? c * (tnew + c) : c;
                v = (cols[n] == lab) ? fv : v;
                if (cols[n] < NCLS)
                    orow[cols[n]] = v * S_C;
            }
        }
    }
}

extern "C" void kernel_launch(void* const* d_in, const int* in_sizes, int n_in,
                              void* d_out, int out_size, void* d_ws, size_t ws_size,
                              hipStream_t stream) {
    const float* emb = (const float*)d_in[0];
    const float* Kg  = (const float*)d_in[1];
    const float* tin = (const float*)d_in[2];
    const int*   lab = (const int*)d_in[3];
    float* out = (float*)d_out;

    char* w = (char*)d_ws;
    u16*   Bn   = (u16*)w;                         // 1564*32768*2 = 102,498,304
    u16*   Aw   = (u16*)(w + 102498304);           // 8*65536*2    =   1,048,576
    float* Af   = (float*)(w + 103546880);         // 1024*512*4   =   2,097,152
    float* kinv = (float*)(w + 105644032);         // CPAD*4       =     400,384
    float* tgt  = (float*)(w + 106044416);
    float* ctmv = (float*)(w + 106048512);
    float* finv = (float*)(w + 106052608);
    float* tnw  = (float*)(w + 106056704);

    norm_emb_k<<<NROWS, 64, 0, stream>>>(emb, Af, Aw);
    transpose_norm_k<<<CPAD / 128, 128, 0, stream>>>(Kg, Bn, kinv);
    target_k<<<NROWS, 64, 0, stream>>>(Af, Bn, kinv, lab, tgt, ctmv, finv);
    tnew_k<<<1, 256, 0, stream>>>(tgt, tin, tnw);
    gemm_k<<<NWG, 256, 0, stream>>>(
        Aw, Bn, kinv, ctmv, finv, lab, tnw, out);
}